// Round 1
// baseline (378.512 us; speedup 1.0000x reference)
//
#include <hip/hip_runtime.h>
#include <stdint.h>

// ---------------------------------------------------------------------------
// LongSelfAttention: x[16384,1024] -> QKV proj -> per-token 16x16 head attn
// -> O proj. All GEMMs in bf16 MFMA (16x16x32), attention core in fp32.
// Workspace layout (bytes):
//   [0,            32 MiB) x_bf16           [16384][1024]
//   [32 MiB,       40 MiB) W^T bf16 x4      [4][1024][1024]  (q,k,v,o)
//   [40 MiB,      136 MiB) qkv bf16         [3][16384][1024]  (attn overwrites q)
// ---------------------------------------------------------------------------

typedef __attribute__((ext_vector_type(8))) short short8;
typedef __attribute__((ext_vector_type(4))) float floatx4;
typedef __attribute__((address_space(1))) unsigned int gu32;
typedef __attribute__((address_space(3))) unsigned int lu32;

#define HID 1024
#define MTOK 16384                 // B*L
#define WELEM (HID * HID)          // 1048576
#define XELEM (MTOK * HID)         // 16777216

__device__ __forceinline__ unsigned short f2bf(float f) {
  union { float f; uint32_t u; } v; v.f = f;
  uint32_t u = v.u;
  u += 0x7fffu + ((u >> 16) & 1u);   // round-to-nearest-even
  return (unsigned short)(u >> 16);
}
__device__ __forceinline__ float bf2f(unsigned short h) {
  union { uint32_t u; float f; } v; v.u = ((uint32_t)h) << 16;
  return v.f;
}

// ---- x fp32 -> bf16, vectorized (float4 in, ushort4 out) ------------------
__global__ __launch_bounds__(256) void cvt_x_kernel(const float* __restrict__ x,
                                                    unsigned short* __restrict__ xb) {
  const int idx = blockIdx.x * 256 + threadIdx.x;
  float4 v = ((const float4*)x)[idx];
  ushort4 o;
  o.x = f2bf(v.x); o.y = f2bf(v.y); o.z = f2bf(v.z); o.w = f2bf(v.w);
  ((ushort4*)xb)[idx] = o;
}

// ---- W [k][n] fp32 -> W^T [n][k] bf16 via 64x64 LDS tile ------------------
__global__ __launch_bounds__(256) void cvt_w_kernel(const float* __restrict__ W0,
                                                    const float* __restrict__ W1,
                                                    const float* __restrict__ W2,
                                                    const float* __restrict__ W3,
                                                    unsigned short* __restrict__ WT) {
  const float* W = (blockIdx.z == 0) ? W0 : (blockIdx.z == 1) ? W1
                   : (blockIdx.z == 2) ? W2 : W3;
  unsigned short* out = WT + (size_t)blockIdx.z * WELEM;
  __shared__ float tile[64][65];
  const int t = threadIdx.x;
  const int n0 = blockIdx.x * 64, k0 = blockIdx.y * 64;
#pragma unroll
  for (int i = 0; i < 4; i++) {
    const int row = i * 16 + (t >> 4);     // k within tile
    const int col = (t & 15) * 4;          // n within tile
    float4 v = *(const float4*)&W[(size_t)(k0 + row) * HID + n0 + col];
    tile[row][col] = v.x; tile[row][col + 1] = v.y;
    tile[row][col + 2] = v.z; tile[row][col + 3] = v.w;
  }
  __syncthreads();
#pragma unroll
  for (int i = 0; i < 4; i++) {
    const int n = i * 16 + (t >> 4);
    const int k = (t & 15) * 4;
    ushort4 o;
    o.x = f2bf(tile[k][n]);     o.y = f2bf(tile[k + 1][n]);
    o.z = f2bf(tile[k + 2][n]); o.w = f2bf(tile[k + 3][n]);
    *(ushort4*)&out[(size_t)(n0 + n) * HID + k0 + k] = o;
  }
}

// ---- m97-style NT GEMM: C[m,n] = A[m,:] . BT[n,:] (+bias[n]) --------------
// 128x128 tile, BK=32, 256 thr = 4 waves, wave computes 64x64 via 4x4 MFMAs.
template <bool BF16_OUT>
__global__ __launch_bounds__(256) void gemm_bt(
    const unsigned short* __restrict__ A,     // [MTOK][HID] bf16
    const unsigned short* __restrict__ BT0,   // [HID][HID] bf16 (+z*WELEM)
    const float* __restrict__ b0, const float* __restrict__ b1,
    const float* __restrict__ b2,
    void* __restrict__ Cv)                    // bf16: +z*XELEM; fp32: d_out
{
  const int z = blockIdx.z;
  const unsigned short* BT = BT0 + (size_t)z * WELEM;
  const float* bias = (z == 0) ? b0 : ((z == 1) ? b1 : b2);
  const int m0 = blockIdx.y * 128;
  const int n0 = blockIdx.x * 128;

  __shared__ unsigned short Als[128 * 32];
  __shared__ unsigned short Bls[128 * 32];

  const int t = threadIdx.x;
  const int wv = t >> 6;
  const int lane = t & 63;
  const int quad = lane >> 4;
  const int r16 = lane & 15;
  const int wr = wv >> 1, wc = wv & 1;

  floatx4 acc[4][4] = {};

  // staging: thread t -> row t/4 (and +64), 16B chunk (t%4)*16
  const int srow = t >> 2;
  const int scol = (t & 3) * 8;
  const unsigned short* Ag = A + (size_t)(m0 + srow) * HID + scol;
  const unsigned short* Bg = BT + (size_t)(n0 + srow) * HID + scol;
  unsigned short* Asl = Als + (wv * 16) * 32;  // wave-uniform LDS base
  unsigned short* Bsl = Bls + (wv * 16) * 32;

  for (int ko = 0; ko < HID; ko += 32) {
    __builtin_amdgcn_global_load_lds((const gu32*)(Ag + ko),            (lu32*)(Asl),            16, 0, 0);
    __builtin_amdgcn_global_load_lds((const gu32*)(Ag + 64 * HID + ko), (lu32*)(Asl + 64 * 32),  16, 0, 0);
    __builtin_amdgcn_global_load_lds((const gu32*)(Bg + ko),            (lu32*)(Bsl),            16, 0, 0);
    __builtin_amdgcn_global_load_lds((const gu32*)(Bg + 64 * HID + ko), (lu32*)(Bsl + 64 * 32),  16, 0, 0);
    __syncthreads();

    short8 a[4], b[4];
#pragma unroll
    for (int i = 0; i < 4; i++)
      a[i] = *(const short8*)(Als + (wr * 64 + i * 16 + r16) * 32 + quad * 8);
#pragma unroll
    for (int j = 0; j < 4; j++)
      b[j] = *(const short8*)(Bls + (wc * 64 + j * 16 + r16) * 32 + quad * 8);
#pragma unroll
    for (int i = 0; i < 4; i++)
#pragma unroll
      for (int j = 0; j < 4; j++)
        acc[i][j] = __builtin_amdgcn_mfma_f32_16x16x32_bf16(a[i], b[j], acc[i][j], 0, 0, 0);
    __syncthreads();
  }

  // epilogue: C/D layout col=lane&15, row=quad*4+reg (measured m89/m91)
#pragma unroll
  for (int j = 0; j < 4; j++) {
    const int col = n0 + wc * 64 + j * 16 + r16;
    const float bb = bias[col];
#pragma unroll
    for (int i = 0; i < 4; i++) {
      const int row0 = m0 + wr * 64 + i * 16 + quad * 4;
#pragma unroll
      for (int rr = 0; rr < 4; rr++) {
        const float val = acc[i][j][rr] + bb;
        if constexpr (BF16_OUT)
          ((unsigned short*)Cv)[(size_t)z * XELEM + (size_t)(row0 + rr) * HID + col] = f2bf(val);
        else
          ((float*)Cv)[(size_t)(row0 + rr) * HID + col] = val;
      }
    }
  }
}

// ---- per-token head attention: one wave per token -------------------------
__global__ __launch_bounds__(256) void attn_kernel(const unsigned short* __restrict__ qkv,
                                                   unsigned short* __restrict__ attn) {
  __shared__ float qs[4][16][68];   // padded: rows land on distinct banks
  __shared__ float ks[4][16][68];
  __shared__ float vs[4][16][68];
  __shared__ float ps[4][16][17];

  const int t = threadIdx.x;
  const int wv = t >> 6, lane = t & 63;
  const size_t base = ((size_t)blockIdx.x * 4 + wv) * HID;

#pragma unroll
  for (int m = 0; m < 3; m++) {
    const unsigned short* src = qkv + (size_t)m * XELEM + base;
    float (*dst)[68] = (m == 0) ? qs[wv] : ((m == 1) ? ks[wv] : vs[wv]);
#pragma unroll
    for (int j = 0; j < 4; j++) {
      const int e0 = j * 256 + lane * 4;     // coalesced 8B/lane
      ushort4 u = *(const ushort4*)(src + e0);
      const int h = e0 >> 6, d = e0 & 63;
      dst[h][d] = bf2f(u.x); dst[h][d + 1] = bf2f(u.y);
      dst[h][d + 2] = bf2f(u.z); dst[h][d + 3] = bf2f(u.w);
    }
  }
  __syncthreads();

  // scores[h][e] = q[h,:].k[e,:] / 8 ; lane -> h=lane/4, e=(lane&3)+4g
  const int h = lane >> 2;
  float4 qv[16];
#pragma unroll
  for (int d4 = 0; d4 < 16; d4++) qv[d4] = *(const float4*)&qs[wv][h][d4 * 4];
#pragma unroll
  for (int g = 0; g < 4; g++) {
    const int e = (lane & 3) + g * 4;
    float s = 0.f;
#pragma unroll
    for (int d4 = 0; d4 < 16; d4++) {
      float4 kv = *(const float4*)&ks[wv][e][d4 * 4];
      s += qv[d4].x * kv.x + qv[d4].y * kv.y + qv[d4].z * kv.z + qv[d4].w * kv.w;
    }
    ps[wv][h][e] = s * 0.125f;
  }
  __syncthreads();

  // softmax over e, one row per lane (lanes 0..15)
  if (lane < 16) {
    float mx = -1e30f;
#pragma unroll
    for (int e = 0; e < 16; e++) mx = fmaxf(mx, ps[wv][lane][e]);
    float pr[16]; float sum = 0.f;
#pragma unroll
    for (int e = 0; e < 16; e++) { float p = __expf(ps[wv][lane][e] - mx); pr[e] = p; sum += p; }
    const float inv = 1.f / sum;
#pragma unroll
    for (int e = 0; e < 16; e++) ps[wv][lane][e] = pr[e] * inv;
  }
  __syncthreads();

  // out[h][d] = sum_e p[h][e] * v[e][d]; lane -> d
  float vreg[16];
#pragma unroll
  for (int e = 0; e < 16; e++) vreg[e] = vs[wv][e][lane];
#pragma unroll
  for (int hh = 0; hh < 16; hh++) {
    float s = 0.f;
#pragma unroll
    for (int e = 0; e < 16; e++) s += ps[wv][hh][e] * vreg[e];
    attn[base + hh * 64 + lane] = f2bf(s);   // overwrites q region (safe)
  }
}

extern "C" void kernel_launch(void* const* d_in, const int* in_sizes, int n_in,
                              void* d_out, int out_size, void* d_ws, size_t ws_size,
                              hipStream_t stream) {
  const float* x  = (const float*)d_in[0];
  const float* Wq = (const float*)d_in[1];
  const float* bq = (const float*)d_in[2];
  const float* Wk = (const float*)d_in[3];
  const float* bk = (const float*)d_in[4];
  const float* Wv = (const float*)d_in[5];
  const float* bv = (const float*)d_in[6];
  const float* Wo = (const float*)d_in[7];
  const float* bo = (const float*)d_in[8];

  char* ws = (char*)d_ws;
  unsigned short* xb  = (unsigned short*)ws;                        // 32 MiB
  unsigned short* wt  = (unsigned short*)(ws + (size_t)XELEM * 2);  // 8 MiB
  unsigned short* qkv = wt + 4 * (size_t)WELEM;                     // 96 MiB

  cvt_x_kernel<<<XELEM / 1024, 256, 0, stream>>>(x, xb);
  cvt_w_kernel<<<dim3(16, 16, 4), 256, 0, stream>>>(Wq, Wk, Wv, Wo, wt);
  gemm_bt<true><<<dim3(8, 128, 3), 256, 0, stream>>>(xb, wt, bq, bk, bv, (void*)qkv);
  attn_kernel<<<4096, 256, 0, stream>>>(qkv, qkv);  // attn overwrites q region
  gemm_bt<false><<<dim3(8, 128, 1), 256, 0, stream>>>(qkv, wt + 3 * (size_t)WELEM,
                                                      bo, bo, bo, d_out);
}

// Round 2
// 363.849 us; speedup vs baseline: 1.0403x; 1.0403x over previous
//
#include <hip/hip_runtime.h>
#include <stdint.h>

// ---------------------------------------------------------------------------
// LongSelfAttention: x[16384,1024] -> QKV proj -> per-token 16x16 head attn
// -> O proj. GEMMs: bf16 MFMA 16x16x32, 128x128 tile, global_load_lds w=16.
// Attention: MFMA scores + shuffle softmax + readlane-FMA PV (no barriers).
// Workspace layout (bytes):
//   [0,            32 MiB) x_bf16           [16384][1024]
//   [32 MiB,       40 MiB) W^T bf16 x4      [4][1024][1024]  (q,k,v,o)
//   [40 MiB,      136 MiB) qkv bf16         [3][16384][1024]  (attn overwrites q)
// ---------------------------------------------------------------------------

typedef __attribute__((ext_vector_type(8))) short short8;
typedef __attribute__((ext_vector_type(4))) float floatx4;
typedef __attribute__((address_space(1))) unsigned int gu32;
typedef __attribute__((address_space(3))) unsigned int lu32;

#define HID 1024
#define MTOK 16384                 // B*L
#define WELEM (HID * HID)          // 1048576
#define XELEM (MTOK * HID)         // 16777216

__device__ __forceinline__ unsigned short f2bf(float f) {
  union { float f; uint32_t u; } v; v.f = f;
  uint32_t u = v.u;
  u += 0x7fffu + ((u >> 16) & 1u);   // round-to-nearest-even
  return (unsigned short)(u >> 16);
}
__device__ __forceinline__ float bf2f(unsigned short h) {
  union { uint32_t u; float f; } v; v.u = ((uint32_t)h) << 16;
  return v.f;
}

// ---- x fp32 -> bf16, vectorized -------------------------------------------
__global__ __launch_bounds__(256) void cvt_x_kernel(const float* __restrict__ x,
                                                    unsigned short* __restrict__ xb) {
  const int idx = blockIdx.x * 256 + threadIdx.x;
  float4 v = ((const float4*)x)[idx];
  ushort4 o;
  o.x = f2bf(v.x); o.y = f2bf(v.y); o.z = f2bf(v.z); o.w = f2bf(v.w);
  ((ushort4*)xb)[idx] = o;
}

// ---- W [k][n] fp32 -> W^T [n][k] bf16 via 64x64 LDS tile ------------------
__global__ __launch_bounds__(256) void cvt_w_kernel(const float* __restrict__ W0,
                                                    const float* __restrict__ W1,
                                                    const float* __restrict__ W2,
                                                    const float* __restrict__ W3,
                                                    unsigned short* __restrict__ WT) {
  const float* W = (blockIdx.z == 0) ? W0 : (blockIdx.z == 1) ? W1
                   : (blockIdx.z == 2) ? W2 : W3;
  unsigned short* out = WT + (size_t)blockIdx.z * WELEM;
  __shared__ float tile[64][65];
  const int t = threadIdx.x;
  const int n0 = blockIdx.x * 64, k0 = blockIdx.y * 64;
#pragma unroll
  for (int i = 0; i < 4; i++) {
    const int row = i * 16 + (t >> 4);     // k within tile
    const int col = (t & 15) * 4;          // n within tile
    float4 v = *(const float4*)&W[(size_t)(k0 + row) * HID + n0 + col];
    tile[row][col] = v.x; tile[row][col + 1] = v.y;
    tile[row][col + 2] = v.z; tile[row][col + 3] = v.w;
  }
  __syncthreads();
#pragma unroll
  for (int i = 0; i < 4; i++) {
    const int n = i * 16 + (t >> 4);
    const int k = (t & 15) * 4;
    ushort4 o;
    o.x = f2bf(tile[k][n]);     o.y = f2bf(tile[k + 1][n]);
    o.z = f2bf(tile[k + 2][n]); o.w = f2bf(tile[k + 3][n]);
    *(ushort4*)&out[(size_t)(n0 + n) * HID + k0 + k] = o;
  }
}

// ---- NT GEMM core: C[m,n] = A[m,:].BT[n,:] + bias[n] ----------------------
// 128x128 tile, BK=32, 4 waves, wave does 64x64 via 4x4 MFMAs. 1D grid with
// XCD-aware swizzle (each XCD keeps an m-band + current B-tile in its L2).
// QKV=true: grid 3072 (128m x 24n over z=0..2), bf16 out to qkv[z].
// QKV=false: grid 1024 (128m x 8n), fp32 out.
template <bool QKV>
__global__ __launch_bounds__(256) void gemm_bt1d(
    const unsigned short* __restrict__ A,     // [MTOK][HID] bf16
    const unsigned short* __restrict__ BTb,   // base of W^T array
    const float* __restrict__ b0, const float* __restrict__ b1,
    const float* __restrict__ b2,
    void* __restrict__ Cv)
{
  // ---- swizzle: dispatch index -> (m-block, n-block) with XCD m-bands ----
  const int i = blockIdx.x;
  const int xcd = i & 7;
  const int j = i >> 3;
  int mb, nb;
  if constexpr (QKV) {
    const int round = j / 192;               // 2 rounds of 64 m-blocks
    const int jj = j - round * 192;
    nb = jj >> 3;                            // 0..23 (n fastest outer)
    mb = xcd * 8 + round * 64 + (jj & 7);    // m fastest inner (band of 8)
  } else {
    const int round = j >> 5;                // 4 rounds of 32 m-blocks
    const int jj = j & 31;
    nb = jj >> 2;                            // 0..7
    mb = xcd * 4 + round * 32 + (jj & 3);    // band of 4
  }
  const int z = QKV ? (nb >> 3) : 0;
  const int n0 = QKV ? ((nb & 7) * 128) : (nb * 128);   // local n within z
  const int m0 = mb * 128;
  const unsigned short* BT = BTb + (size_t)(QKV ? z : 3) * WELEM;
  const float* bias = QKV ? ((z == 0) ? b0 : ((z == 1) ? b1 : b2)) : b0;

  __shared__ unsigned short Als[128 * 32];
  __shared__ unsigned short Bls[128 * 32];

  const int t = threadIdx.x;
  const int wv = t >> 6;
  const int lane = t & 63;
  const int quad = lane >> 4;
  const int r16 = lane & 15;
  const int wr = wv >> 1, wc = wv & 1;

  floatx4 acc[4][4] = {};

  const int srow = t >> 2;
  const int scol = (t & 3) * 8;
  const unsigned short* Ag = A + (size_t)(m0 + srow) * HID + scol;
  const unsigned short* Bg = BT + (size_t)(n0 + srow) * HID + scol;
  unsigned short* Asl = Als + (wv * 16) * 32;  // wave-uniform LDS base
  unsigned short* Bsl = Bls + (wv * 16) * 32;

  for (int ko = 0; ko < HID; ko += 32) {
    __builtin_amdgcn_global_load_lds((const gu32*)(Ag + ko),            (lu32*)(Asl),            16, 0, 0);
    __builtin_amdgcn_global_load_lds((const gu32*)(Ag + 64 * HID + ko), (lu32*)(Asl + 64 * 32),  16, 0, 0);
    __builtin_amdgcn_global_load_lds((const gu32*)(Bg + ko),            (lu32*)(Bsl),            16, 0, 0);
    __builtin_amdgcn_global_load_lds((const gu32*)(Bg + 64 * HID + ko), (lu32*)(Bsl + 64 * 32),  16, 0, 0);
    __syncthreads();

    short8 a[4], b[4];
#pragma unroll
    for (int ii = 0; ii < 4; ii++)
      a[ii] = *(const short8*)(Als + (wr * 64 + ii * 16 + r16) * 32 + quad * 8);
#pragma unroll
    for (int jj = 0; jj < 4; jj++)
      b[jj] = *(const short8*)(Bls + (wc * 64 + jj * 16 + r16) * 32 + quad * 8);
#pragma unroll
    for (int ii = 0; ii < 4; ii++)
#pragma unroll
      for (int jj = 0; jj < 4; jj++)
        acc[ii][jj] = __builtin_amdgcn_mfma_f32_16x16x32_bf16(a[ii], b[jj], acc[ii][jj], 0, 0, 0);
    __syncthreads();
  }

  // epilogue: C/D layout col=lane&15, row=quad*4+reg (measured m89/m91)
#pragma unroll
  for (int jj = 0; jj < 4; jj++) {
    const int col = n0 + wc * 64 + jj * 16 + r16;
    const float bb = bias[col];
#pragma unroll
    for (int ii = 0; ii < 4; ii++) {
      const int row0 = m0 + wr * 64 + ii * 16 + quad * 4;
#pragma unroll
      for (int rr = 0; rr < 4; rr++) {
        const float val = acc[ii][jj][rr] + bb;
        if constexpr (QKV)
          ((unsigned short*)Cv)[(size_t)z * XELEM + (size_t)(row0 + rr) * HID + col] = f2bf(val);
        else
          ((float*)Cv)[(size_t)(row0 + rr) * HID + col] = val;
      }
    }
  }
}

// ---- per-token head attention: one wave per token, MFMA scores ------------
// scores C-layout: lane holds col(e)=lane&15, rows(h)=quad*4+rr. Softmax =
// 16-lane shuffle butterfly per quad. PV: lane owns d=lane; p(h,e) broadcast
// via __shfl from lane (h>>2)*16+e. No __syncthreads (waves token-private).
__global__ __launch_bounds__(256) void attn_kernel(const unsigned short* qkv,
                                                   unsigned short* attn) {
  __shared__ float vs[4][16][68];            // v fp32, 16B-aligned rows

  const int t = threadIdx.x;
  const int wv = t >> 6, lane = t & 63;
  const int quad = lane >> 4, r16 = lane & 15;
  const size_t base = ((size_t)blockIdx.x * 4 + wv) * HID;
  const unsigned short* qp = qkv + base;                     // q[16][64]
  const unsigned short* kp = qkv + (size_t)XELEM + base;     // k[16][64]
  const unsigned short* vp = qkv + 2 * (size_t)XELEM + base; // v[16][64]

  // A/B fragments direct from global (row-major 16B chunks; verified pattern)
  short8 qf0 = *(const short8*)(qp + r16 * 64 + quad * 8);
  short8 qf1 = *(const short8*)(qp + r16 * 64 + quad * 8 + 32);
  short8 kf0 = *(const short8*)(kp + r16 * 64 + quad * 8);
  short8 kf1 = *(const short8*)(kp + r16 * 64 + quad * 8 + 32);

  // stage v into LDS as fp32 (coalesced 8B/lane reads)
#pragma unroll
  for (int jj = 0; jj < 4; jj++) {
    const int e0 = jj * 256 + lane * 4;
    ushort4 u = *(const ushort4*)(vp + e0);
    const int e = e0 >> 6, d = e0 & 63;
    float4 w; w.x = bf2f(u.x); w.y = bf2f(u.y); w.z = bf2f(u.z); w.w = bf2f(u.w);
    *(float4*)&vs[wv][e][d] = w;
  }

  // scores = q.k^T / 8  (fp32 accum in MFMA)
  floatx4 sc = {0.f, 0.f, 0.f, 0.f};
  sc = __builtin_amdgcn_mfma_f32_16x16x32_bf16(qf0, kf0, sc, 0, 0, 0);
  sc = __builtin_amdgcn_mfma_f32_16x16x32_bf16(qf1, kf1, sc, 0, 0, 0);

  // softmax over e (across the 16 lanes of each quad), per row rr
  float p[4];
#pragma unroll
  for (int rr = 0; rr < 4; rr++) {
    float s = sc[rr] * 0.125f;
    float m = s;
#pragma unroll
    for (int off = 1; off < 16; off <<= 1) m = fmaxf(m, __shfl_xor(m, off));
    float ex = __expf(s - m);
    float sum = ex;
#pragma unroll
    for (int off = 1; off < 16; off <<= 1) sum += __shfl_xor(sum, off);
    p[rr] = ex / sum;
  }

  // lane owns column d=lane of v
  float vcol[16];
#pragma unroll
  for (int e = 0; e < 16; e++) vcol[e] = vs[wv][e][lane];

  // out[h][d] = sum_e p[h][e] * v[e][d]; store bf16 (overwrites q: safe)
#pragma unroll
  for (int hh = 0; hh < 16; hh++) {
    float acc = 0.f;
#pragma unroll
    for (int e = 0; e < 16; e++)
      acc += __shfl(p[hh & 3], (hh >> 2) * 16 + e) * vcol[e];
    attn[base + hh * 64 + lane] = f2bf(acc);
  }
}

extern "C" void kernel_launch(void* const* d_in, const int* in_sizes, int n_in,
                              void* d_out, int out_size, void* d_ws, size_t ws_size,
                              hipStream_t stream) {
  const float* x  = (const float*)d_in[0];
  const float* Wq = (const float*)d_in[1];
  const float* bq = (const float*)d_in[2];
  const float* Wk = (const float*)d_in[3];
  const float* bk = (const float*)d_in[4];
  const float* Wv = (const float*)d_in[5];
  const float* bv = (const float*)d_in[6];
  const float* Wo = (const float*)d_in[7];
  const float* bo = (const float*)d_in[8];

  char* ws = (char*)d_ws;
  unsigned short* xb  = (unsigned short*)ws;                        // 32 MiB
  unsigned short* wt  = (unsigned short*)(ws + (size_t)XELEM * 2);  // 8 MiB
  unsigned short* qkv = wt + 4 * (size_t)WELEM;                     // 96 MiB

  cvt_x_kernel<<<XELEM / 1024, 256, 0, stream>>>(x, xb);
  cvt_w_kernel<<<dim3(16, 16, 4), 256, 0, stream>>>(Wq, Wk, Wv, Wo, wt);
  gemm_bt1d<true><<<3072, 256, 0, stream>>>(xb, wt, bq, bk, bv, (void*)qkv);
  attn_kernel<<<4096, 256, 0, stream>>>(qkv, qkv);  // attn overwrites q region
  gemm_bt1d<false><<<1024, 256, 0, stream>>>(qkv, wt, bo, bo, bo, d_out);
}

// Round 3
// 332.990 us; speedup vs baseline: 1.1367x; 1.0927x over previous
//
#include <hip/hip_runtime.h>
#include <stdint.h>

// ---------------------------------------------------------------------------
// LongSelfAttention: x[16384,1024] -> QKV proj -> per-token 16x16 head attn
// -> O proj. GEMMs: bf16 MFMA 16x16x32, 128x128 tile, global_load_lds w=16,
// XCD-swizzled 1D grid. Attention: MFMA scores + shuffle softmax + MFMA PV
// (P transposed to A-layout via per-wave LDS; V DMA'd bf16, skewed chunks).
// Workspace layout (bytes):
//   [0,            32 MiB) x_bf16           [16384][1024]
//   [32 MiB,       40 MiB) W^T bf16 x4      [4][1024][1024]  (q,k,v,o)
//   [40 MiB,      136 MiB) qkv bf16         [3][16384][1024]  (attn overwrites q)
// ---------------------------------------------------------------------------

typedef __attribute__((ext_vector_type(8))) short short8;
typedef __attribute__((ext_vector_type(4))) float floatx4;
typedef __attribute__((address_space(1))) unsigned int gu32;
typedef __attribute__((address_space(3))) unsigned int lu32;

#define HID 1024
#define MTOK 16384                 // B*L
#define WELEM (HID * HID)          // 1048576
#define XELEM (MTOK * HID)         // 16777216

__device__ __forceinline__ unsigned short f2bf(float f) {
  union { float f; uint32_t u; } v; v.f = f;
  uint32_t u = v.u;
  u += 0x7fffu + ((u >> 16) & 1u);   // round-to-nearest-even
  return (unsigned short)(u >> 16);
}

// ---- x fp32 -> bf16, vectorized -------------------------------------------
__global__ __launch_bounds__(256) void cvt_x_kernel(const float* __restrict__ x,
                                                    unsigned short* __restrict__ xb) {
  const int idx = blockIdx.x * 256 + threadIdx.x;
  float4 v = ((const float4*)x)[idx];
  ushort4 o;
  o.x = f2bf(v.x); o.y = f2bf(v.y); o.z = f2bf(v.z); o.w = f2bf(v.w);
  ((ushort4*)xb)[idx] = o;
}

// ---- W [k][n] fp32 -> W^T [n][k] bf16 via 64x64 LDS tile ------------------
__global__ __launch_bounds__(256) void cvt_w_kernel(const float* __restrict__ W0,
                                                    const float* __restrict__ W1,
                                                    const float* __restrict__ W2,
                                                    const float* __restrict__ W3,
                                                    unsigned short* __restrict__ WT) {
  const float* W = (blockIdx.z == 0) ? W0 : (blockIdx.z == 1) ? W1
                   : (blockIdx.z == 2) ? W2 : W3;
  unsigned short* out = WT + (size_t)blockIdx.z * WELEM;
  __shared__ float tile[64][65];
  const int t = threadIdx.x;
  const int n0 = blockIdx.x * 64, k0 = blockIdx.y * 64;
#pragma unroll
  for (int i = 0; i < 4; i++) {
    const int row = i * 16 + (t >> 4);     // k within tile
    const int col = (t & 15) * 4;          // n within tile
    float4 v = *(const float4*)&W[(size_t)(k0 + row) * HID + n0 + col];
    tile[row][col] = v.x; tile[row][col + 1] = v.y;
    tile[row][col + 2] = v.z; tile[row][col + 3] = v.w;
  }
  __syncthreads();
#pragma unroll
  for (int i = 0; i < 4; i++) {
    const int n = i * 16 + (t >> 4);
    const int k = (t & 15) * 4;
    ushort4 o;
    o.x = f2bf(tile[k][n]);     o.y = f2bf(tile[k + 1][n]);
    o.z = f2bf(tile[k + 2][n]); o.w = f2bf(tile[k + 3][n]);
    *(ushort4*)&out[(size_t)(n0 + n) * HID + k0 + k] = o;
  }
}

// ---- NT GEMM core: C[m,n] = A[m,:].BT[n,:] + bias[n] ----------------------
// 128x128 tile, BK=32, 4 waves, wave does 64x64 via 4x4 MFMAs. 1D grid with
// XCD-aware swizzle (each XCD keeps an m-band + current B-tile in its L2).
template <bool QKV>
__global__ __launch_bounds__(256) void gemm_bt1d(
    const unsigned short* __restrict__ A,     // [MTOK][HID] bf16
    const unsigned short* __restrict__ BTb,   // base of W^T array
    const float* __restrict__ b0, const float* __restrict__ b1,
    const float* __restrict__ b2,
    void* __restrict__ Cv)
{
  const int i = blockIdx.x;
  const int xcd = i & 7;
  const int j = i >> 3;
  int mb, nb;
  if constexpr (QKV) {
    const int round = j / 192;               // 2 rounds of 64 m-blocks
    const int jj = j - round * 192;
    nb = jj >> 3;                            // 0..23 (n fastest outer)
    mb = xcd * 8 + round * 64 + (jj & 7);    // m fastest inner (band of 8)
  } else {
    const int round = j >> 5;                // 4 rounds of 32 m-blocks
    const int jj = j & 31;
    nb = jj >> 2;                            // 0..7
    mb = xcd * 4 + round * 32 + (jj & 3);    // band of 4
  }
  const int z = QKV ? (nb >> 3) : 0;
  const int n0 = QKV ? ((nb & 7) * 128) : (nb * 128);
  const int m0 = mb * 128;
  const unsigned short* BT = BTb + (size_t)(QKV ? z : 3) * WELEM;
  const float* bias = QKV ? ((z == 0) ? b0 : ((z == 1) ? b1 : b2)) : b0;

  __shared__ unsigned short Als[128 * 32];
  __shared__ unsigned short Bls[128 * 32];

  const int t = threadIdx.x;
  const int wv = t >> 6;
  const int lane = t & 63;
  const int quad = lane >> 4;
  const int r16 = lane & 15;
  const int wr = wv >> 1, wc = wv & 1;

  floatx4 acc[4][4] = {};

  const int srow = t >> 2;
  const int scol = (t & 3) * 8;
  const unsigned short* Ag = A + (size_t)(m0 + srow) * HID + scol;
  const unsigned short* Bg = BT + (size_t)(n0 + srow) * HID + scol;
  unsigned short* Asl = Als + (wv * 16) * 32;  // wave-uniform LDS base
  unsigned short* Bsl = Bls + (wv * 16) * 32;

  for (int ko = 0; ko < HID; ko += 32) {
    __builtin_amdgcn_global_load_lds((const gu32*)(Ag + ko),            (lu32*)(Asl),            16, 0, 0);
    __builtin_amdgcn_global_load_lds((const gu32*)(Ag + 64 * HID + ko), (lu32*)(Asl + 64 * 32),  16, 0, 0);
    __builtin_amdgcn_global_load_lds((const gu32*)(Bg + ko),            (lu32*)(Bsl),            16, 0, 0);
    __builtin_amdgcn_global_load_lds((const gu32*)(Bg + 64 * HID + ko), (lu32*)(Bsl + 64 * 32),  16, 0, 0);
    __syncthreads();

    short8 a[4], b[4];
#pragma unroll
    for (int ii = 0; ii < 4; ii++)
      a[ii] = *(const short8*)(Als + (wr * 64 + ii * 16 + r16) * 32 + quad * 8);
#pragma unroll
    for (int jj = 0; jj < 4; jj++)
      b[jj] = *(const short8*)(Bls + (wc * 64 + jj * 16 + r16) * 32 + quad * 8);
#pragma unroll
    for (int ii = 0; ii < 4; ii++)
#pragma unroll
      for (int jj = 0; jj < 4; jj++)
        acc[ii][jj] = __builtin_amdgcn_mfma_f32_16x16x32_bf16(a[ii], b[jj], acc[ii][jj], 0, 0, 0);
    __syncthreads();
  }

  // epilogue: C/D layout col=lane&15, row=quad*4+reg (measured m89/m91)
#pragma unroll
  for (int jj = 0; jj < 4; jj++) {
    const int col = n0 + wc * 64 + jj * 16 + r16;
    const float bb = bias[col];
#pragma unroll
    for (int ii = 0; ii < 4; ii++) {
      const int row0 = m0 + wr * 64 + ii * 16 + quad * 4;
#pragma unroll
      for (int rr = 0; rr < 4; rr++) {
        const float val = acc[ii][jj][rr] + bb;
        if constexpr (QKV)
          ((unsigned short*)Cv)[(size_t)z * XELEM + (size_t)(row0 + rr) * HID + col] = f2bf(val);
        else
          ((float*)Cv)[(size_t)(row0 + rr) * HID + col] = val;
      }
    }
  }
}

// ---- per-token head attention: one wave per token, all-MFMA ---------------
// scores: 2x mfma_16x16x32 (C: col e=lane&15, row h=quad*4+rr).
// softmax: 16-lane shuffle butterfly per quad row.
// P -> A-layout via per-wave LDS (bf16, row stride 24 ushorts, <=2-way).
// V: DMA'd bf16 [16][64], chunk1 skewed +32B -> B-frag ds_read_u16 2-way free.
// PV: 4x mfma_16x16x32 with k=16..31 zeroed (K=16 real).
__global__ __launch_bounds__(256) void attn_kernel(const unsigned short* qkv,
                                                   unsigned short* attn) {
  __shared__ unsigned short vls[4][1056];    // per wave: rows0-7 @0, rows8-15 @528
  __shared__ unsigned short pls[4][16 * 24]; // P bf16, stride 24 ushorts (48B)

  const int t = threadIdx.x;
  const int wv = t >> 6, lane = t & 63;
  const int quad = lane >> 4, r16 = lane & 15;
  const size_t base = ((size_t)blockIdx.x * 4 + wv) * HID;
  const unsigned short* qp = qkv + base;                     // q[16][64]
  const unsigned short* kp = qkv + (size_t)XELEM + base;     // k[16][64]
  const unsigned short* vp = qkv + 2 * (size_t)XELEM + base; // v[16][64]

  // V -> LDS (bf16, no conversion), 16B/lane DMA; chunk1 skewed +32B
  __builtin_amdgcn_global_load_lds((const gu32*)(vp + lane * 8),       (lu32*)&vls[wv][0],   16, 0, 0);
  __builtin_amdgcn_global_load_lds((const gu32*)(vp + 512 + lane * 8), (lu32*)&vls[wv][528], 16, 0, 0);

  // q/k A/B fragments direct from global (verified m97-pattern layout)
  short8 qf0 = *(const short8*)(qp + r16 * 64 + quad * 8);
  short8 qf1 = *(const short8*)(qp + r16 * 64 + quad * 8 + 32);
  short8 kf0 = *(const short8*)(kp + r16 * 64 + quad * 8);
  short8 kf1 = *(const short8*)(kp + r16 * 64 + quad * 8 + 32);

  // scores = q.k^T / 8 (fp32 accum in MFMA)
  floatx4 sc = {0.f, 0.f, 0.f, 0.f};
  sc = __builtin_amdgcn_mfma_f32_16x16x32_bf16(qf0, kf0, sc, 0, 0, 0);
  sc = __builtin_amdgcn_mfma_f32_16x16x32_bf16(qf1, kf1, sc, 0, 0, 0);

  // softmax over e (across 16 lanes of each quad), write P bf16 to LDS
#pragma unroll
  for (int rr = 0; rr < 4; rr++) {
    float s = sc[rr] * 0.125f;
    float m = s;
#pragma unroll
    for (int off = 1; off < 16; off <<= 1) m = fmaxf(m, __shfl_xor(m, off));
    float ex = __expf(s - m);
    float sum = ex;
#pragma unroll
    for (int off = 1; off < 16; off <<= 1) sum += __shfl_xor(sum, off);
    pls[wv][(quad * 4 + rr) * 24 + r16] = f2bf(ex / sum);   // P[h][e]
  }

  __syncthreads();   // covers V DMA completion + cross-lane P visibility

  // A-frag: P[m=r16][k=quad*8+j] (quads 0,1 real; 2,3 zero)
  const short8 zero8 = {0, 0, 0, 0, 0, 0, 0, 0};
  short8 af = zero8;
  short8 bf[4] = {zero8, zero8, zero8, zero8};
  if (quad < 2) {
    af = *(const short8*)&pls[wv][r16 * 24 + quad * 8];
    // B-frag: VT[n=c*16+r16][k=e=quad*8+j] = vls[e-row][c*16+r16]
#pragma unroll
    for (int c = 0; c < 4; c++)
#pragma unroll
      for (int jj = 0; jj < 8; jj++)
        bf[c][jj] = (short)vls[wv][quad * 528 + jj * 64 + c * 16 + r16];
  }

  floatx4 ov[4];
#pragma unroll
  for (int c = 0; c < 4; c++) {
    floatx4 z = {0.f, 0.f, 0.f, 0.f};
    ov[c] = __builtin_amdgcn_mfma_f32_16x16x32_bf16(af, bf[c], z, 0, 0, 0);
  }

  // C-layout: out[h=quad*4+rr][d=c*16+r16]; store bf16 (overwrites q: safe)
#pragma unroll
  for (int rr = 0; rr < 4; rr++)
#pragma unroll
    for (int c = 0; c < 4; c++)
      attn[base + (size_t)(quad * 4 + rr) * 64 + c * 16 + r16] = f2bf(ov[c][rr]);
}

extern "C" void kernel_launch(void* const* d_in, const int* in_sizes, int n_in,
                              void* d_out, int out_size, void* d_ws, size_t ws_size,
                              hipStream_t stream) {
  const float* x  = (const float*)d_in[0];
  const float* Wq = (const float*)d_in[1];
  const float* bq = (const float*)d_in[2];
  const float* Wk = (const float*)d_in[3];
  const float* bk = (const float*)d_in[4];
  const float* Wv = (const float*)d_in[5];
  const float* bv = (const float*)d_in[6];
  const float* Wo = (const float*)d_in[7];
  const float* bo = (const float*)d_in[8];

  char* ws = (char*)d_ws;
  unsigned short* xb  = (unsigned short*)ws;                        // 32 MiB
  unsigned short* wt  = (unsigned short*)(ws + (size_t)XELEM * 2);  // 8 MiB
  unsigned short* qkv = wt + 4 * (size_t)WELEM;                     // 96 MiB

  cvt_x_kernel<<<XELEM / 1024, 256, 0, stream>>>(x, xb);
  cvt_w_kernel<<<dim3(16, 16, 4), 256, 0, stream>>>(Wq, Wk, Wv, Wo, wt);
  gemm_bt1d<true><<<3072, 256, 0, stream>>>(xb, wt, bq, bk, bv, (void*)qkv);
  attn_kernel<<<4096, 256, 0, stream>>>(qkv, qkv);  // attn overwrites q region
  gemm_bt1d<false><<<1024, 256, 0, stream>>>(qkv, wt, bo, bo, bo, d_out);
}